// Round 3
// baseline (194.445 us; speedup 1.0000x reference)
//
#include <hip/hip_runtime.h>

// YOLO v1-style loss, forward only.
// prediction: [32768, 7, 7, 12] f32   (B=2 boxes * 5 + C=2 classes)
// target:     [32768, 7, 7, 7]  f32   (x,y,w,h,obj, c0,c1)
// output:     scalar f32
//
// Round-3 structure: LDS-staged. Global loads are lane-contiguous float4
// (16 B/lane -> 16 lines per wave instruction). LDS layouts chosen for
// conflict-free strided reads: pred padded 12->13 floats/cell (gcd(13,32)=1),
// targ linear 7 floats/cell (gcd(7,32)=1).

constexpr int S = 7;
constexpr int CELLS = 32768 * S * S;          // 1,605,632
constexpr int CPB = 256;                      // cells per block == threads
constexpr int NBLK = CELLS / CPB;             // 6272
constexpr float LAMBDA_COORD = 5.0f;
constexpr float LAMBDA_NOOBJ = 0.5f;
constexpr float INV_S = 1.0f / 7.0f;

__device__ __forceinline__ float cell_loss(const float* p, const float* t,
                                           float fcol, float frow) {
    float x0 = p[0], y0 = p[1], w0 = p[2], h0 = p[3], c0 = p[4];
    float x1 = p[5], y1 = p[6], w1 = p[7], h1 = p[8], c1 = p[9];
    float q0 = p[10], q1 = p[11];
    float tx = t[0], ty = t[1], tw = t[2], th = t[3], tp = t[4];
    float s0 = t[5], s1 = t[6];

    // target corners + area
    float tcx = (tx + fcol) * INV_S, tcy = (ty + frow) * INV_S;
    float tX1 = tcx - tw * 0.5f, tY1 = tcy - th * 0.5f;
    float tX2 = tcx + tw * 0.5f, tY2 = tcy + th * 0.5f;
    float ta = fabsf((tX2 - tX1) * (tY2 - tY1));

    // box 0
    float cx0 = (x0 + fcol) * INV_S, cy0 = (y0 + frow) * INV_S;
    float aX1 = cx0 - w0 * 0.5f, aY1 = cy0 - h0 * 0.5f;
    float aX2 = cx0 + w0 * 0.5f, aY2 = cy0 + h0 * 0.5f;
    float inter0 = fmaxf(fminf(aX2, tX2) - fmaxf(aX1, tX1), 0.0f) *
                   fmaxf(fminf(aY2, tY2) - fmaxf(aY1, tY1), 0.0f);
    float ar0 = fabsf((aX2 - aX1) * (aY2 - aY1));
    float u0 = ar0 + ta - inter0 + 1e-8f;      // > 0 always

    // box 1
    float cx1 = (x1 + fcol) * INV_S, cy1 = (y1 + frow) * INV_S;
    float bX1 = cx1 - w1 * 0.5f, bY1 = cy1 - h1 * 0.5f;
    float bX2 = cx1 + w1 * 0.5f, bY2 = cy1 + h1 * 0.5f;
    float inter1 = fmaxf(fminf(bX2, tX2) - fmaxf(bX1, tX1), 0.0f) *
                   fmaxf(fminf(bY2, tY2) - fmaxf(bY1, tY1), 0.0f);
    float ar1 = fabsf((bX2 - bX1) * (bY2 - bY1));
    float u1 = ar1 + ta - inter1 + 1e-8f;

    // argmax(iou): box1 iff iou1 > iou0  <=>  inter1*u0 > inter0*u1  (u > 0)
    bool sel1 = inter1 * u0 > inter0 * u1;
    float px = sel1 ? x1 : x0;
    float py = sel1 ? y1 : y0;
    float pw = sel1 ? w1 : w0;
    float ph = sel1 ? h1 : h0;
    float pp = sel1 ? c1 : c0;

    float obj = (tp > 0.0f) ? 1.0f : 0.0f;
    float noobj = 1.0f - obj;

    float dx = px - tx, dy = py - ty;
    float centre = dx * dx + dy * dy;

    float sgnw = (pw > 0.0f) ? 1.0f : ((pw < 0.0f) ? -1.0f : 0.0f);
    float sgnh = (ph > 0.0f) ? 1.0f : ((ph < 0.0f) ? -1.0f : 0.0f);
    float dw = sgnw * sqrtf(fabsf(pw) + 1e-6f) - sqrtf(tw);
    float dh = sgnh * sqrtf(fabsf(ph) + 1e-6f) - sqrtf(th);
    float dim = dw * dw + dh * dh;

    float dconf = pp - tp;
    float n0 = c0 - tp, n1 = c1 - tp;
    float dc0 = q0 - s0, dc1 = q1 - s1;

    return obj * (LAMBDA_COORD * (centre + dim) + dconf * dconf + dc0 * dc0 + dc1 * dc1)
         + noobj * LAMBDA_NOOBJ * (n0 * n0 + n1 * n1);
}

__global__ __launch_bounds__(256)
void yolo_loss_kernel(const float* __restrict__ pred,
                      const float* __restrict__ targ,
                      double* __restrict__ ws) {
    __shared__ float sp[CPB * 13];   // pred: 12 -> 13 floats/cell (pad)
    __shared__ float st[CPB * 7];    // targ: linear, stride-7 reads are conflict-free

    const int t = threadIdx.x;
    const int base = blockIdx.x * CPB;

    // ---- stage pred: 256 cells * 12 floats = 768 float4, lane-contiguous ----
    const float4* pg = reinterpret_cast<const float4*>(pred + (size_t)base * 12);
    #pragma unroll
    for (int k = 0; k < 3; ++k) {
        int f = t + 256 * k;            // float4 index 0..767
        float4 v = pg[f];
        int cell = f / 3;               // 3 float4 per cell
        int slot = f - 3 * cell;        // 0..2
        float* dst = &sp[cell * 13 + slot * 4];
        dst[0] = v.x; dst[1] = v.y; dst[2] = v.z; dst[3] = v.w;
    }

    // ---- stage targ: 256 cells * 7 floats = 448 float4, lane-contiguous ----
    const float4* tg = reinterpret_cast<const float4*>(targ + (size_t)base * 7);
    {
        float4 v = tg[t];
        reinterpret_cast<float4*>(st)[t] = v;
    }
    if (t < 192) {
        float4 v = tg[t + 256];
        reinterpret_cast<float4*>(st)[t + 256] = v;
    }

    __syncthreads();

    // ---- compute own cell from LDS ----
    int idx = base + t;
    int j = idx % S;
    int i = (idx / S) % S;
    float acc = cell_loss(&sp[t * 13], &st[t * 7], (float)j, (float)i);

    // ---- block reduction in double: wave shuffle -> LDS -> one atomic ----
    double v = (double)acc;
    #pragma unroll
    for (int off = 32; off > 0; off >>= 1)
        v += __shfl_down(v, off, 64);

    __shared__ double sm[4];
    int lane = threadIdx.x & 63;
    int wid  = threadIdx.x >> 6;
    if (lane == 0) sm[wid] = v;
    __syncthreads();
    if (threadIdx.x == 0) {
        double s = sm[0] + sm[1] + sm[2] + sm[3];
        atomicAdd(ws, s);
    }
}

__global__ void finalize_kernel(const double* __restrict__ ws, float* __restrict__ out) {
    out[0] = (float)ws[0];
}

extern "C" void kernel_launch(void* const* d_in, const int* in_sizes, int n_in,
                              void* d_out, int out_size, void* d_ws, size_t ws_size,
                              hipStream_t stream) {
    const float* pred = (const float*)d_in[0];
    const float* targ = (const float*)d_in[1];
    float* out = (float*)d_out;
    double* ws = (double*)d_ws;

    hipMemsetAsync(ws, 0, sizeof(double), stream);

    yolo_loss_kernel<<<NBLK, 256, 0, stream>>>(pred, targ, ws);
    finalize_kernel<<<1, 1, 0, stream>>>(ws, out);
}

// Round 4
// 163.510 us; speedup vs baseline: 1.1892x; 1.1892x over previous
//
#include <hip/hip_runtime.h>

// YOLO v1-style loss, forward only.
// prediction: [32768, 7, 7, 12] f32   (B=2 boxes * 5 + C=2 classes)
// target:     [32768, 7, 7, 7]  f32   (x,y,w,h,obj, c0,c1)
// output:     scalar f32
//
// Round-4: round-2 structure (4 cells/thread, 19 float4 loads up-front) with
//  (a) __launch_bounds__(256,1): lift VGPR cap (was 32 -> loads serialized),
//      keep all 19 loads in flight per thread;
//  (b) no global atomics: per-block partial -> d_ws[block], second kernel
//      reduces (rounds 1/3 showed 6272 same-address f64 atomics ~ +30us tail).

constexpr int S = 7;
constexpr int CELLS = 32768 * S * S;          // 1,605,632
constexpr int CPT = 4;                        // cells per thread
constexpr int NTHREADS = CELLS / CPT;         // 401,408
constexpr int NBLK = NTHREADS / 256;          // 1568
constexpr float LAMBDA_COORD = 5.0f;
constexpr float LAMBDA_NOOBJ = 0.5f;
constexpr float INV_S = 1.0f / 7.0f;

__device__ __forceinline__ float cell_loss(const float* p, const float* t,
                                           float fcol, float frow) {
    float x0 = p[0], y0 = p[1], w0 = p[2], h0 = p[3], c0 = p[4];
    float x1 = p[5], y1 = p[6], w1 = p[7], h1 = p[8], c1 = p[9];
    float q0 = p[10], q1 = p[11];
    float tx = t[0], ty = t[1], tw = t[2], th = t[3], tp = t[4];
    float s0 = t[5], s1 = t[6];

    // target corners + area
    float tcx = (tx + fcol) * INV_S, tcy = (ty + frow) * INV_S;
    float tX1 = tcx - tw * 0.5f, tY1 = tcy - th * 0.5f;
    float tX2 = tcx + tw * 0.5f, tY2 = tcy + th * 0.5f;
    float ta = fabsf((tX2 - tX1) * (tY2 - tY1));

    // box 0
    float cx0 = (x0 + fcol) * INV_S, cy0 = (y0 + frow) * INV_S;
    float aX1 = cx0 - w0 * 0.5f, aY1 = cy0 - h0 * 0.5f;
    float aX2 = cx0 + w0 * 0.5f, aY2 = cy0 + h0 * 0.5f;
    float inter0 = fmaxf(fminf(aX2, tX2) - fmaxf(aX1, tX1), 0.0f) *
                   fmaxf(fminf(aY2, tY2) - fmaxf(aY1, tY1), 0.0f);
    float ar0 = fabsf((aX2 - aX1) * (aY2 - aY1));
    float u0 = ar0 + ta - inter0 + 1e-8f;      // > 0 always

    // box 1
    float cx1 = (x1 + fcol) * INV_S, cy1 = (y1 + frow) * INV_S;
    float bX1 = cx1 - w1 * 0.5f, bY1 = cy1 - h1 * 0.5f;
    float bX2 = cx1 + w1 * 0.5f, bY2 = cy1 + h1 * 0.5f;
    float inter1 = fmaxf(fminf(bX2, tX2) - fmaxf(bX1, tX1), 0.0f) *
                   fmaxf(fminf(bY2, tY2) - fmaxf(bY1, tY1), 0.0f);
    float ar1 = fabsf((bX2 - bX1) * (bY2 - bY1));
    float u1 = ar1 + ta - inter1 + 1e-8f;

    // argmax(iou): box1 iff iou1 > iou0  <=>  inter1*u0 > inter0*u1  (u > 0)
    bool sel1 = inter1 * u0 > inter0 * u1;
    float px = sel1 ? x1 : x0;
    float py = sel1 ? y1 : y0;
    float pw = sel1 ? w1 : w0;
    float ph = sel1 ? h1 : h0;
    float pp = sel1 ? c1 : c0;

    float obj = (tp > 0.0f) ? 1.0f : 0.0f;
    float noobj = 1.0f - obj;

    float dx = px - tx, dy = py - ty;
    float centre = dx * dx + dy * dy;

    float sgnw = (pw > 0.0f) ? 1.0f : ((pw < 0.0f) ? -1.0f : 0.0f);
    float sgnh = (ph > 0.0f) ? 1.0f : ((ph < 0.0f) ? -1.0f : 0.0f);
    float dw = sgnw * sqrtf(fabsf(pw) + 1e-6f) - sqrtf(tw);
    float dh = sgnh * sqrtf(fabsf(ph) + 1e-6f) - sqrtf(th);
    float dim = dw * dw + dh * dh;

    float dconf = pp - tp;
    float n0 = c0 - tp, n1 = c1 - tp;
    float dc0 = q0 - s0, dc1 = q1 - s1;

    return obj * (LAMBDA_COORD * (centre + dim) + dconf * dconf + dc0 * dc0 + dc1 * dc1)
         + noobj * LAMBDA_NOOBJ * (n0 * n0 + n1 * n1);
}

__global__ __launch_bounds__(256, 1)
void yolo_loss_kernel(const float* __restrict__ pred,
                      const float* __restrict__ targ,
                      double* __restrict__ ws) {
    int tid = blockIdx.x * blockDim.x + threadIdx.x;
    int base = tid * CPT;

    // issue all 19 float4 loads up-front; (256,1) gives the register room
    float4 pv[12];
    float4 tv[7];
    const float4* p4 = reinterpret_cast<const float4*>(pred + (size_t)base * 12);
    const float4* t4 = reinterpret_cast<const float4*>(targ + (size_t)base * 7);
    #pragma unroll
    for (int k = 0; k < 12; ++k) pv[k] = p4[k];
    #pragma unroll
    for (int k = 0; k < 7; ++k) tv[k] = t4[k];

    const float* pf = reinterpret_cast<const float*>(pv);
    const float* tf = reinterpret_cast<const float*>(tv);

    int j = base % S;
    int i = (base / S) % S;

    float acc = 0.0f;
    #pragma unroll
    for (int k = 0; k < CPT; ++k) {
        acc += cell_loss(pf + k * 12, tf + k * 7, (float)j, (float)i);
        if (++j == S) { j = 0; if (++i == S) i = 0; }
    }

    // block reduction in double: wave shuffle -> LDS -> one plain store
    double v = (double)acc;
    #pragma unroll
    for (int off = 32; off > 0; off >>= 1)
        v += __shfl_down(v, off, 64);

    __shared__ double sm[4];
    int lane = threadIdx.x & 63;
    int wid  = threadIdx.x >> 6;
    if (lane == 0) sm[wid] = v;
    __syncthreads();
    if (threadIdx.x == 0)
        ws[blockIdx.x] = sm[0] + sm[1] + sm[2] + sm[3];   // NO atomic
}

__global__ __launch_bounds__(256)
void reduce_kernel(const double* __restrict__ ws, float* __restrict__ out) {
    int t = threadIdx.x;
    double s = 0.0;
    for (int idx = t; idx < NBLK; idx += 256) s += ws[idx];

    #pragma unroll
    for (int off = 32; off > 0; off >>= 1)
        s += __shfl_down(s, off, 64);

    __shared__ double sm[4];
    int lane = t & 63, wid = t >> 6;
    if (lane == 0) sm[wid] = s;
    __syncthreads();
    if (t == 0) out[0] = (float)(sm[0] + sm[1] + sm[2] + sm[3]);
}

extern "C" void kernel_launch(void* const* d_in, const int* in_sizes, int n_in,
                              void* d_out, int out_size, void* d_ws, size_t ws_size,
                              hipStream_t stream) {
    const float* pred = (const float*)d_in[0];
    const float* targ = (const float*)d_in[1];
    float* out = (float*)d_out;
    double* ws = (double*)d_ws;

    yolo_loss_kernel<<<NBLK, 256, 0, stream>>>(pred, targ, ws);
    reduce_kernel<<<1, 256, 0, stream>>>(ws, out);
}

// Round 11
// 151.278 us; speedup vs baseline: 1.2854x; 1.0809x over previous
//
#include <hip/hip_runtime.h>

// YOLO v1-style loss, forward only.
// prediction: [32768, 7, 7, 12] f32   (B=2 boxes * 5 + C=2 classes)
// target:     [32768, 7, 7, 7]  f32   (x,y,w,h,obj, c0,c1)
// output:     scalar f32
//
// Round-5 kernel (resubmit x6; prior attempts hit GPU-acquisition timeouts):
//  (a) asm keep-alive fence between load phase and compute: forces ALL 19
//      global_load_dwordx4 to issue back-to-back (VGPR should jump 32->~100;
//      round 4 showed launch_bounds alone leaves VGPR=32 and loads batched);
//  (b) 128-thread blocks x 3136 (12.25/CU) for balance; per-wave shuffle
//      reduction -> plain store per wave; no LDS, no syncthreads, no atomics.

constexpr int S = 7;
constexpr int CELLS = 32768 * S * S;          // 1,605,632
constexpr int CPT = 4;                        // cells per thread
constexpr int TPB = 128;                      // threads per block (2 waves)
constexpr int NTHREADS = CELLS / CPT;         // 401,408
constexpr int NBLK = NTHREADS / TPB;          // 3136
constexpr int NWAVES = NTHREADS / 64;         // 6,272
constexpr float LAMBDA_COORD = 5.0f;
constexpr float LAMBDA_NOOBJ = 0.5f;
constexpr float INV_S = 1.0f / 7.0f;

__device__ __forceinline__ float cell_loss(const float* p, const float* t,
                                           float fcol, float frow) {
    float x0 = p[0], y0 = p[1], w0 = p[2], h0 = p[3], c0 = p[4];
    float x1 = p[5], y1 = p[6], w1 = p[7], h1 = p[8], c1 = p[9];
    float q0 = p[10], q1 = p[11];
    float tx = t[0], ty = t[1], tw = t[2], th = t[3], tp = t[4];
    float s0 = t[5], s1 = t[6];

    // target corners + area
    float tcx = (tx + fcol) * INV_S, tcy = (ty + frow) * INV_S;
    float tX1 = tcx - tw * 0.5f, tY1 = tcy - th * 0.5f;
    float tX2 = tcx + tw * 0.5f, tY2 = tcy + th * 0.5f;
    float ta = fabsf((tX2 - tX1) * (tY2 - tY1));

    // box 0
    float cx0 = (x0 + fcol) * INV_S, cy0 = (y0 + frow) * INV_S;
    float aX1 = cx0 - w0 * 0.5f, aY1 = cy0 - h0 * 0.5f;
    float aX2 = cx0 + w0 * 0.5f, aY2 = cy0 + h0 * 0.5f;
    float inter0 = fmaxf(fminf(aX2, tX2) - fmaxf(aX1, tX1), 0.0f) *
                   fmaxf(fminf(aY2, tY2) - fmaxf(aY1, tY1), 0.0f);
    float ar0 = fabsf((aX2 - aX1) * (aY2 - aY1));
    float u0 = ar0 + ta - inter0 + 1e-8f;      // > 0 always

    // box 1
    float cx1 = (x1 + fcol) * INV_S, cy1 = (y1 + frow) * INV_S;
    float bX1 = cx1 - w1 * 0.5f, bY1 = cy1 - h1 * 0.5f;
    float bX2 = cx1 + w1 * 0.5f, bY2 = cy1 + h1 * 0.5f;
    float inter1 = fmaxf(fminf(bX2, tX2) - fmaxf(bX1, tX1), 0.0f) *
                   fmaxf(fminf(bY2, tY2) - fmaxf(bY1, tY1), 0.0f);
    float ar1 = fabsf((bX2 - bX1) * (bY2 - bY1));
    float u1 = ar1 + ta - inter1 + 1e-8f;

    // argmax(iou): box1 iff iou1 > iou0  <=>  inter1*u0 > inter0*u1  (u > 0)
    bool sel1 = inter1 * u0 > inter0 * u1;
    float px = sel1 ? x1 : x0;
    float py = sel1 ? y1 : y0;
    float pw = sel1 ? w1 : w0;
    float ph = sel1 ? h1 : h0;
    float pp = sel1 ? c1 : c0;

    float obj = (tp > 0.0f) ? 1.0f : 0.0f;
    float noobj = 1.0f - obj;

    float dx = px - tx, dy = py - ty;
    float centre = dx * dx + dy * dy;

    float sgnw = (pw > 0.0f) ? 1.0f : ((pw < 0.0f) ? -1.0f : 0.0f);
    float sgnh = (ph > 0.0f) ? 1.0f : ((ph < 0.0f) ? -1.0f : 0.0f);
    float dw = sgnw * sqrtf(fabsf(pw) + 1e-6f) - sqrtf(tw);
    float dh = sgnh * sqrtf(fabsf(ph) + 1e-6f) - sqrtf(th);
    float dim = dw * dw + dh * dh;

    float dconf = pp - tp;
    float n0 = c0 - tp, n1 = c1 - tp;
    float dc0 = q0 - s0, dc1 = q1 - s1;

    return obj * (LAMBDA_COORD * (centre + dim) + dconf * dconf + dc0 * dc0 + dc1 * dc1)
         + noobj * LAMBDA_NOOBJ * (n0 * n0 + n1 * n1);
}

__global__ __launch_bounds__(TPB, 1)
void yolo_loss_kernel(const float* __restrict__ pred,
                      const float* __restrict__ targ,
                      double* __restrict__ ws) {
    int tid = blockIdx.x * blockDim.x + threadIdx.x;
    int base = tid * CPT;

    float4 pv[12];
    float4 tv[7];
    const float4* p4 = reinterpret_cast<const float4*>(pred + (size_t)base * 12);
    const float4* t4 = reinterpret_cast<const float4*>(targ + (size_t)base * 7);
    #pragma unroll
    for (int k = 0; k < 12; ++k) pv[k] = p4[k];
    #pragma unroll
    for (int k = 0; k < 7; ++k) tv[k] = t4[k];

    // MLP fence: force every load's result to be materialized here, so all 19
    // global_load_dwordx4 issue before any compute (defeats compiler batching).
    #pragma unroll
    for (int k = 0; k < 12; ++k)
        asm volatile("" : "+v"(pv[k].x), "+v"(pv[k].y), "+v"(pv[k].z), "+v"(pv[k].w));
    #pragma unroll
    for (int k = 0; k < 7; ++k)
        asm volatile("" : "+v"(tv[k].x), "+v"(tv[k].y), "+v"(tv[k].z), "+v"(tv[k].w));

    const float* pf = reinterpret_cast<const float*>(pv);
    const float* tf = reinterpret_cast<const float*>(tv);

    int j = base % S;
    int i = (base / S) % S;

    float acc = 0.0f;
    #pragma unroll
    for (int k = 0; k < CPT; ++k) {
        acc += cell_loss(pf + k * 12, tf + k * 7, (float)j, (float)i);
        if (++j == S) { j = 0; if (++i == S) i = 0; }
    }

    // per-wave reduction in double -> one plain 8B store per wave
    double v = (double)acc;
    #pragma unroll
    for (int off = 32; off > 0; off >>= 1)
        v += __shfl_down(v, off, 64);

    if ((threadIdx.x & 63) == 0)
        ws[tid >> 6] = v;                      // global wave index
}

__global__ __launch_bounds__(256)
void reduce_kernel(const double* __restrict__ ws, float* __restrict__ out) {
    int t = threadIdx.x;
    double s = 0.0;
    for (int idx = t; idx < NWAVES; idx += 256) s += ws[idx];

    #pragma unroll
    for (int off = 32; off > 0; off >>= 1)
        s += __shfl_down(s, off, 64);

    __shared__ double sm[4];
    int lane = t & 63, wid = t >> 6;
    if (lane == 0) sm[wid] = s;
    __syncthreads();
    if (t == 0) out[0] = (float)(sm[0] + sm[1] + sm[2] + sm[3]);
}

extern "C" void kernel_launch(void* const* d_in, const int* in_sizes, int n_in,
                              void* d_out, int out_size, void* d_ws, size_t ws_size,
                              hipStream_t stream) {
    const float* pred = (const float*)d_in[0];
    const float* targ = (const float*)d_in[1];
    float* out = (float*)d_out;
    double* ws = (double*)d_ws;

    yolo_loss_kernel<<<NBLK, TPB, 0, stream>>>(pred, targ, ws);
    reduce_kernel<<<1, 256, 0, stream>>>(ws, out);
}